// Round 1
// baseline (1347.745 us; speedup 1.0000x reference)
//
#include <hip/hip_runtime.h>
#include <cstdint>
#include <cstddef>

// PCFG inside algorithm. B=8, n=28, NT=32, T=64, ST=96.
// beta structure: width-0 rows valid only on [NT,96) (terminals, = unary),
// width>=1 rows valid only on [0,32) (nonterminals). So numer support is
// quadrants: TT (w==1), TN (k=0), NT (k=w-1), NN (middle splits).

__device__ __forceinline__ float dot4acc(float4 m, float4 t, float acc) {
    return fmaf(m.x, t.x, fmaf(m.y, t.y, fmaf(m.z, t.z, fmaf(m.w, t.w, acc))));
}

// ---- mrule[b][a] = max over 96x96 of rule_scores[b][a] ----
__global__ __launch_bounds__(256) void mrule_kernel(const float* __restrict__ rule,
                                                    float* __restrict__ mrule) {
    int a = blockIdx.x, b = blockIdx.y, tid = threadIdx.x;
    const float* base = rule + (size_t)(b * 32 + a) * 9216;
    float v = -3.0e38f;
    for (int i = tid; i < 9216; i += 256) v = fmaxf(v, base[i]);
    for (int off = 32; off > 0; off >>= 1) v = fmaxf(v, __shfl_xor(v, off, 64));
    __shared__ float red[4];
    if ((tid & 63) == 0) red[tid >> 6] = v;
    __syncthreads();
    if (tid == 0)
        mrule[b * 32 + a] = fmaxf(fmaxf(red[0], red[1]), fmaxf(red[2], red[3]));
}

// ---- bmax[b][0][s] = max_t unary[b][s][t] ----
__global__ void bmax0_kernel(const float* __restrict__ unary,
                             float* __restrict__ bmax, int n) {
    int s = blockIdx.x, b = blockIdx.y, tid = threadIdx.x; // block = 64
    float v = unary[((size_t)(b * n + s)) * 64 + tid];
    for (int off = 32; off > 0; off >>= 1) v = fmaxf(v, __shfl_xor(v, off, 64));
    if (tid == 0) bmax[(b * n + 0) * n + s] = v;
}

// ---- pack erule = exp(rule - mrule) into quadrant arrays, [c][a][4] layout ----
// E_TT: 1024 c's (l,r in [32,96)); E_TN: 512 (l in [32,96), r in [0,32));
// E_NT: 512 (l in [0,32), r in [32,96)); E_NN: 256 (l,r in [0,32)).
__global__ __launch_bounds__(256) void pack_kernel(const float* __restrict__ rule,
                                                   const float* __restrict__ mrule,
                                                   float* __restrict__ E_TT,
                                                   float* __restrict__ E_TN,
                                                   float* __restrict__ E_NT,
                                                   float* __restrict__ E_NN) {
    int b = blockIdx.y, tid = threadIdx.x;
    int a = tid & 31;
    int cc = blockIdx.x * 8 + (tid >> 5); // 0..2303
    float mr = mrule[b * 32 + a];
    int l, r;
    float* dst;
    if (cc < 1024) {
        int flat = cc * 4;
        l = 32 + (flat >> 6); r = 32 + (flat & 63);
        dst = E_TT + ((size_t)(b * 1024 + cc) * 32 + a) * 4;
    } else if (cc < 1536) {
        int flat = (cc - 1024) * 4;
        l = 32 + (flat >> 5); r = flat & 31;
        dst = E_TN + ((size_t)(b * 512 + (cc - 1024)) * 32 + a) * 4;
    } else if (cc < 2048) {
        int flat = (cc - 1536) * 4;
        l = flat >> 6; r = 32 + (flat & 63);
        dst = E_NT + ((size_t)(b * 512 + (cc - 1536)) * 32 + a) * 4;
    } else {
        int flat = (cc - 2048) * 4;
        l = flat >> 5; r = flat & 31;
        dst = E_NN + ((size_t)(b * 256 + (cc - 2048)) * 32 + a) * 4;
    }
    const float4 v = *(const float4*)(rule + (((size_t)(b * 32 + a) * 96 + l) * 96 + r));
    float4 o;
    o.x = expf(v.x - mr); o.y = expf(v.y - mr);
    o.z = expf(v.z - mr); o.w = expf(v.w - mr);
    *(float4*)dst = o;
}

// ---- one CKY step: width w, block per (span s, batch b) ----
__global__ __launch_bounds__(256) void step_kernel(
    const float* __restrict__ unary,   // B,n,64
    const float* __restrict__ mrule,   // B,32
    float* __restrict__ bmax,          // B,n,n
    float* __restrict__ beta_n,        // B,n,n,32  (widths >= 1)
    const float* __restrict__ E_TT, const float* __restrict__ E_TN,
    const float* __restrict__ E_NT, const float* __restrict__ E_NN,
    int w, int n) {
    int s = blockIdx.x, b = blockIdx.y, tid = threadIdx.x;

    __shared__ float elN[28][32];
    __shared__ float erN[28][32];
    __shared__ float el0T[64], erT[64];
    __shared__ float mlv[28], msum[28];
    __shared__ float red[8][32];
    __shared__ __align__(16) float numer[5120];

    // Phase 1: split maxes
    if (tid < w) {
        float ml = bmax[(b * n + tid) * n + s];
        float mr = bmax[(b * n + (w - 1 - tid)) * n + (s + tid + 1)];
        mlv[tid] = ml;
        msum[tid] = ml + mr;
    }
    __syncthreads();
    float M = -3.0e38f;
    for (int k = 0; k < w; ++k) M = fmaxf(M, msum[k]);

    // Phase 2: exp tables.  el*er = exp(left + right - M)
    if (tid < 64) {
        el0T[tid] = expf(unary[((size_t)(b * n + s)) * 64 + tid] - mlv[0]);
    } else if (tid < 128) {
        int t = tid - 64;
        erT[t] = expf(unary[((size_t)(b * n + s + w)) * 64 + t] + mlv[w - 1] - M);
    }
    {
        int half = (w - 1) * 32;
        for (int idx = tid; idx < (w - 1) * 64; idx += 256) {
            if (idx < half) {
                int k = 1 + (idx >> 5), l = idx & 31;
                elN[k][l] = expf(beta_n[(((size_t)(b * n + k)) * n + s) * 32 + l] - mlv[k]);
            } else {
                int j = idx - half;
                int k = j >> 5, r = j & 31;
                erN[k][r] = expf(
                    beta_n[(((size_t)(b * n + (w - 1 - k))) * n + (s + k + 1)) * 32 + r] +
                    mlv[k] - M);
            }
        }
    }
    __syncthreads();

    // Phase 3: numer quadrants in LDS
    if (w == 1) {
        for (int f = tid; f < 4096; f += 256)
            numer[f] = el0T[f >> 6] * erT[f & 63];
    } else {
        for (int f = tid; f < 2048; f += 256)
            numer[f] = el0T[f >> 5] * erN[0][f & 31];
        for (int f = tid; f < 2048; f += 256)
            numer[2048 + f] = elN[w - 1][f >> 6] * erT[f & 63];
        if (w >= 3) {
            for (int f = tid; f < 1024; f += 256) {
                int l = f >> 5, r = f & 31;
                float acc = 0.f;
                for (int k = 1; k <= w - 2; ++k) acc += elN[k][l] * erN[k][r];
                numer[4096 + f] = acc;
            }
        }
    }
    __syncthreads();

    // Phase 4: contraction total[a] = sum_c <numer4[c], E[b][c][a]>
    int g = tid >> 5, a = tid & 31;
    float acc = 0.f;
    const float4* n4 = (const float4*)numer;
    if (w == 1) {
        const float4* e = (const float4*)E_TT + (size_t)b * 1024 * 32;
        for (int c = g; c < 1024; c += 8)
            acc = dot4acc(n4[c], e[c * 32 + a], acc);
    } else {
        const float4* e1 = (const float4*)E_TN + (size_t)b * 512 * 32;
        for (int c = g; c < 512; c += 8)
            acc = dot4acc(n4[c], e1[c * 32 + a], acc);
        const float4* e2 = (const float4*)E_NT + (size_t)b * 512 * 32;
        for (int c = g; c < 512; c += 8)
            acc = dot4acc(n4[512 + c], e2[c * 32 + a], acc);
        if (w >= 3) {
            const float4* e3 = (const float4*)E_NN + (size_t)b * 256 * 32;
            for (int c = g; c < 256; c += 8)
                acc = dot4acc(n4[1024 + c], e3[c * 32 + a], acc);
        }
    }
    red[g][a] = acc;
    __syncthreads();

    // Phase 5: reduce, log, write beta + bmax
    if (tid < 32) {
        float total = 0.f;
        for (int gg = 0; gg < 8; ++gg) total += red[gg][tid];
        float score = logf(total) + M + mrule[b * 32 + tid];
        beta_n[(((size_t)(b * n + w)) * n + s) * 32 + tid] = score;
        float v = score;
        for (int off = 16; off > 0; off >>= 1) v = fmaxf(v, __shfl_xor(v, off, 32));
        if (tid == 0) bmax[(b * n + w) * n + s] = v;
    }
}

// ---- final: out[b] = logsumexp_a(beta[b][n-1][0][a] + root[b][a]) ----
__global__ void final_kernel(const float* __restrict__ beta_n,
                             const float* __restrict__ root,
                             float* __restrict__ out, int n) {
    int b = blockIdx.x, a = threadIdx.x; // block = 32
    float v = beta_n[(((size_t)(b * n + (n - 1))) * n + 0) * 32 + a] + root[b * 32 + a];
    float m = v;
    for (int off = 16; off > 0; off >>= 1) m = fmaxf(m, __shfl_xor(m, off, 32));
    float e = expf(v - m);
    for (int off = 16; off > 0; off >>= 1) e += __shfl_xor(e, off, 32);
    if (a == 0) out[b] = m + logf(e);
}

extern "C" void kernel_launch(void* const* d_in, const int* in_sizes, int n_in,
                              void* d_out, int out_size, void* d_ws, size_t ws_size,
                              hipStream_t stream) {
    const float* unary = (const float*)d_in[0]; // B,n,64
    const float* rule  = (const float*)d_in[1]; // B,32,96,96
    const float* root  = (const float*)d_in[2]; // B,32
    float* out = (float*)d_out;

    const int B = in_sizes[2] / 32;
    const int n = in_sizes[0] / (B * 64);

    // carve workspace (floats)
    float* ws = (float*)d_ws;
    float* mrule  = ws;                                  // B*32
    float* bmax   = mrule + (size_t)B * 32;              // B*n*n
    float* beta_n = bmax + (size_t)B * n * n;            // B*n*n*32
    float* E_TT   = beta_n + (size_t)B * n * n * 32;     // B*1024*32*4
    float* E_TN   = E_TT + (size_t)B * 131072;           // B*512*32*4
    float* E_NT   = E_TN + (size_t)B * 65536;            // B*512*32*4
    float* E_NN   = E_NT + (size_t)B * 65536;            // B*256*32*4

    mrule_kernel<<<dim3(32, B), 256, 0, stream>>>(rule, mrule);
    bmax0_kernel<<<dim3(n, B), 64, 0, stream>>>(unary, bmax, n);
    pack_kernel<<<dim3(288, B), 256, 0, stream>>>(rule, mrule, E_TT, E_TN, E_NT, E_NN);

    for (int w = 1; w < n; ++w) {
        step_kernel<<<dim3(n - w, B), 256, 0, stream>>>(
            unary, mrule, bmax, beta_n, E_TT, E_TN, E_NT, E_NN, w, n);
    }
    final_kernel<<<dim3(B), 32, 0, stream>>>(beta_n, root, out, n);
}

// Round 2
// 1155.677 us; speedup vs baseline: 1.1662x; 1.1662x over previous
//
#include <hip/hip_runtime.h>
#include <cstdint>
#include <cstddef>

// PCFG inside algorithm. B=8, n=28, NT=32, T=64, ST=96.
// Quadrant decomposition of the (l,r) support:
//   TT (w==1 only): l,r terminal (64x64 = 4096 pairs = 1024 float4-cols)
//   TN (k==0):      l terminal, r nonterminal (2048 pairs = 512 c4)
//   NT (k==w-1):    l nonterminal, r terminal (2048 pairs = 512 c4)
//   NN (1<=k<=w-2): both nonterminal (1024 pairs = 256 c4)
// E tables packed [c4][a][4] so contraction is float4 dot per (c4, a).
//
// Step kernel: grid = (chunks, B). Each block owns a 64-c4 chunk of one
// quadrant, stages its 32KB E-chunk in LDS ONCE, then loops over all spans.
// The per-step chunk-reduction + log + bmax is fused into the NEXT step's
// prologue (redundant but bitwise-identical per same-b block). Partial/M
// buffers ping-pong between steps.

#define PCH 20   // max chunks per (b) per step
#define PS  27   // max spans per step

__device__ __forceinline__ float dot4acc(float4 m, float4 t, float acc) {
    return fmaf(m.x, t.x, fmaf(m.y, t.y, fmaf(m.z, t.z, fmaf(m.w, t.w, acc))));
}

// ---- mrule[b][a] = max over 96x96 of rule_scores[b][a] ----
__global__ __launch_bounds__(256) void mrule_kernel(const float* __restrict__ rule,
                                                    float* __restrict__ mrule) {
    int a = blockIdx.x, b = blockIdx.y, tid = threadIdx.x;
    const float* base = rule + (size_t)(b * 32 + a) * 9216;
    float v = -3.0e38f;
    for (int i = tid; i < 9216; i += 256) v = fmaxf(v, base[i]);
    for (int off = 32; off > 0; off >>= 1) v = fmaxf(v, __shfl_xor(v, off, 64));
    __shared__ float red[4];
    if ((tid & 63) == 0) red[tid >> 6] = v;
    __syncthreads();
    if (tid == 0)
        mrule[b * 32 + a] = fmaxf(fmaxf(red[0], red[1]), fmaxf(red[2], red[3]));
}

// ---- bmax[b][0][s] = max_t unary[b][s][t] ----
__global__ void bmax0_kernel(const float* __restrict__ unary,
                             float* __restrict__ bmax, int n) {
    int s = blockIdx.x, b = blockIdx.y, tid = threadIdx.x; // block = 64
    float v = unary[((size_t)(b * n + s)) * 64 + tid];
    for (int off = 32; off > 0; off >>= 1) v = fmaxf(v, __shfl_xor(v, off, 64));
    if (tid == 0) bmax[(b * n + 0) * n + s] = v;
}

// ---- pack erule = exp(rule - mrule) into quadrant arrays, [c4][a][4] layout ----
__global__ __launch_bounds__(256) void pack_kernel(const float* __restrict__ rule,
                                                   const float* __restrict__ mrule,
                                                   float* __restrict__ E_TT,
                                                   float* __restrict__ E_TN,
                                                   float* __restrict__ E_NT,
                                                   float* __restrict__ E_NN) {
    int b = blockIdx.y, tid = threadIdx.x;
    int a = tid & 31;
    int cc = blockIdx.x * 8 + (tid >> 5); // 0..2303
    float mr = mrule[b * 32 + a];
    int l, r;
    float* dst;
    if (cc < 1024) {
        int flat = cc * 4;
        l = 32 + (flat >> 6); r = 32 + (flat & 63);
        dst = E_TT + ((size_t)(b * 1024 + cc) * 32 + a) * 4;
    } else if (cc < 1536) {
        int flat = (cc - 1024) * 4;
        l = 32 + (flat >> 5); r = flat & 31;
        dst = E_TN + ((size_t)(b * 512 + (cc - 1024)) * 32 + a) * 4;
    } else if (cc < 2048) {
        int flat = (cc - 1536) * 4;
        l = flat >> 6; r = 32 + (flat & 63);
        dst = E_NT + ((size_t)(b * 512 + (cc - 1536)) * 32 + a) * 4;
    } else {
        int flat = (cc - 2048) * 4;
        l = flat >> 5; r = flat & 31;
        dst = E_NN + ((size_t)(b * 256 + (cc - 2048)) * 32 + a) * 4;
    }
    const float4 v = *(const float4*)(rule + (((size_t)(b * 32 + a) * 96 + l) * 96 + r));
    float4 o;
    o.x = expf(v.x - mr); o.y = expf(v.y - mr);
    o.z = expf(v.z - mr); o.w = expf(v.w - mr);
    *(float4*)dst = o;
}

// ---- one CKY step, chunked over the c-dimension ----
__global__ __launch_bounds__(256) void step_kernel(
    const float* __restrict__ unary,   // B,n,64
    const float* __restrict__ mrule,   // B,32
    float* __restrict__ bmax,          // B,n,n
    float* __restrict__ beta_n,        // B,n,n,32  (widths >= 1)
    const float* __restrict__ E_TT, const float* __restrict__ E_TN,
    const float* __restrict__ E_NT, const float* __restrict__ E_NN,
    const float* __restrict__ partial_in, float* __restrict__ partial_out,
    const float* __restrict__ Min, float* __restrict__ Mout,
    int w, int n) {
    int b = blockIdx.y, ch = blockIdx.x, tid = threadIdx.x;
    int S = n - w;

    __shared__ __align__(16) float4 eLds[2048];       // 32KB E chunk
    __shared__ __align__(16) float numerLds[256];     // 64 c4
    __shared__ float betaPrev[28 * 32];
    __shared__ float bmaxPrev[28];
    __shared__ float elN[28 * 32], erN[28 * 32];
    __shared__ float el0T[64], erT[64];
    __shared__ float mlv[28], msum[28];
    __shared__ float red[8 * 32];

    // quadrant select
    int quad, base;
    const float4* Esrc;
    if (w == 1)      { quad = 0; base = ch * 64;        Esrc = (const float4*)E_TT + (size_t)b * 1024 * 32; }
    else if (ch < 8) { quad = 1; base = ch * 64;        Esrc = (const float4*)E_TN + (size_t)b * 512 * 32; }
    else if (ch < 16){ quad = 2; base = (ch - 8) * 64;  Esrc = (const float4*)E_NT + (size_t)b * 512 * 32; }
    else             { quad = 3; base = (ch - 16) * 64; Esrc = (const float4*)E_NN + (size_t)b * 256 * 32; }

    // issue E-chunk load first (independent of prologue)
    {
        const float4* src = Esrc + (size_t)base * 32;
        #pragma unroll
        for (int i = 0; i < 8; ++i) eLds[tid + i * 256] = src[tid + i * 256];
    }

    // prologue: finalize previous width from partials (redundant per same-b block)
    if (w >= 2) {
        int wp = w - 1, Sp = n - wp;
        int CHp = (wp <= 2) ? 16 : 20;
        const float* pin = partial_in + (size_t)b * PCH * PS * 32;
        for (int e = tid; e < Sp * 32; e += 256) {
            int s = e >> 5, a = e & 31;
            float t = 0.f;
            for (int c = 0; c < CHp; ++c) t += pin[c * (PS * 32) + e];
            float score = logf(t) + Min[b * PS + s] + mrule[b * 32 + a];
            beta_n[(((size_t)b * n + wp) * n + s) * 32 + a] = score;
            betaPrev[e] = score;
        }
        __syncthreads();
        if (tid < Sp) {
            float m = -3.0e38f;
            for (int a = 0; a < 32; ++a) m = fmaxf(m, betaPrev[tid * 32 + a]);
            bmaxPrev[tid] = m;
            bmax[(b * n + wp) * n + tid] = m;
        }
    }
    __syncthreads();

    int g = tid >> 5, a = tid & 31;

    for (int s = 0; s < S; ++s) {
        __syncthreads();
        // phase 1: split maxes
        if (tid < w) {
            int k = tid;
            float ml = (k == 0) ? bmax[(b * n + 0) * n + s]
                     : (k == w - 1) ? bmaxPrev[s]
                     : bmax[(b * n + k) * n + s];
            int wr = w - 1 - k;
            float mr = (wr == 0) ? bmax[(b * n + 0) * n + (s + k + 1)]
                     : (k == 0) ? bmaxPrev[s + 1]
                     : bmax[(b * n + wr) * n + (s + k + 1)];
            mlv[k] = ml;
            msum[k] = ml + mr;
        }
        __syncthreads();
        float M = msum[0];
        for (int k = 1; k < w; ++k) M = fmaxf(M, msum[k]);

        // phase 2: exp tables
        if (tid < 64) {
            el0T[tid] = expf(unary[((size_t)(b * n + s)) * 64 + tid] - mlv[0]);
        } else if (tid < 128) {
            int t = tid - 64;
            erT[t] = expf(unary[((size_t)(b * n + s + w)) * 64 + t] + mlv[w - 1] - M);
        }
        {
            int half = (w - 1) * 32;
            for (int idx = tid; idx < (w - 1) * 64; idx += 256) {
                if (idx < half) {
                    int k = 1 + (idx >> 5), l = idx & 31;
                    float src = (k == w - 1) ? betaPrev[s * 32 + l]
                              : beta_n[(((size_t)b * n + k) * n + s) * 32 + l];
                    elN[k * 32 + l] = expf(src - mlv[k]);
                } else {
                    int j = idx - half;
                    int k = j >> 5, r = j & 31;
                    float src = (k == 0) ? betaPrev[(s + 1) * 32 + r]
                              : beta_n[(((size_t)b * n + (w - 1 - k)) * n + (s + k + 1)) * 32 + r];
                    erN[k * 32 + r] = expf(src + mlv[k] - M);
                }
            }
        }
        __syncthreads();

        // phase 3: numer sub-chunk (256 pairs)
        {
            int p = base * 4 + tid;
            float v;
            if (quad == 0)      v = el0T[p >> 6] * erT[p & 63];
            else if (quad == 1) v = el0T[p >> 5] * erN[p & 31];
            else if (quad == 2) v = elN[(w - 1) * 32 + (p >> 6)] * erT[p & 63];
            else {
                int l = p >> 5, r = p & 31;
                float acc = 0.f;
                for (int k = 1; k <= w - 2; ++k)
                    acc = fmaf(elN[k * 32 + l], erN[k * 32 + r], acc);
                v = acc;
            }
            numerLds[tid] = v;
        }
        __syncthreads();

        // phase 4: contract against LDS E-chunk
        {
            const float4* n4 = (const float4*)numerLds;
            float acc = 0.f;
            #pragma unroll
            for (int i = 0; i < 8; ++i) {
                int c = g + i * 8;
                acc = dot4acc(n4[c], eLds[c * 32 + a], acc);
            }
            red[g * 32 + a] = acc;
        }
        __syncthreads();

        // phase 5: per-chunk partial write
        if (tid < 32) {
            float t = 0.f;
            for (int gg = 0; gg < 8; ++gg) t += red[gg * 32 + tid];
            partial_out[(((size_t)b * PCH + ch) * PS + s) * 32 + tid] = t;
        }
        if (tid == 0) Mout[b * PS + s] = M;
    }
}

// ---- final: reduce last width's partials, add root, logsumexp ----
__global__ void final_kernel(const float* __restrict__ partial_in,
                             const float* __restrict__ Min,
                             const float* __restrict__ mrule,
                             const float* __restrict__ root,
                             float* __restrict__ out, int n) {
    int b = blockIdx.x, a = threadIdx.x; // block = 32
    int CHp = ((n - 1) <= 2) ? 16 : 20;
    const float* pin = partial_in + (size_t)b * PCH * PS * 32;
    float t = 0.f;
    for (int c = 0; c < CHp; ++c) t += pin[c * (PS * 32) + a]; // span 0
    float v = logf(t) + Min[b * PS] + mrule[b * 32 + a] + root[b * 32 + a];
    float m = v;
    for (int off = 16; off > 0; off >>= 1) m = fmaxf(m, __shfl_xor(m, off, 32));
    float e = expf(v - m);
    for (int off = 16; off > 0; off >>= 1) e += __shfl_xor(e, off, 32);
    if (a == 0) out[b] = m + logf(e);
}

extern "C" void kernel_launch(void* const* d_in, const int* in_sizes, int n_in,
                              void* d_out, int out_size, void* d_ws, size_t ws_size,
                              hipStream_t stream) {
    const float* unary = (const float*)d_in[0]; // B,n,64
    const float* rule  = (const float*)d_in[1]; // B,32,96,96
    const float* root  = (const float*)d_in[2]; // B,32
    float* out = (float*)d_out;

    const int B = in_sizes[2] / 32;
    const int n = in_sizes[0] / (B * 64);

    // carve workspace (floats)
    float* ws = (float*)d_ws;
    float* mrule   = ws;                                  // B*32
    float* bmax    = mrule + (size_t)B * 32;              // B*n*n
    float* beta_n  = bmax + (size_t)B * n * n;            // B*n*n*32
    float* E_TT    = beta_n + (size_t)B * n * n * 32;     // B*1024*32*4
    float* E_TN    = E_TT + (size_t)B * 131072;           // B*512*32*4
    float* E_NT    = E_TN + (size_t)B * 65536;            // B*512*32*4
    float* E_NN    = E_NT + (size_t)B * 65536;            // B*256*32*4
    float* partA   = E_NN + (size_t)B * 32768;            // B*PCH*PS*32
    float* partB   = partA + (size_t)B * PCH * PS * 32;
    float* MbufA   = partB + (size_t)B * PCH * PS * 32;   // B*PS
    float* MbufB   = MbufA + (size_t)B * PS;

    mrule_kernel<<<dim3(32, B), 256, 0, stream>>>(rule, mrule);
    bmax0_kernel<<<dim3(n, B), 64, 0, stream>>>(unary, bmax, n);
    pack_kernel<<<dim3(288, B), 256, 0, stream>>>(rule, mrule, E_TT, E_TN, E_NT, E_NN);

    float* pbuf[2] = { partA, partB };
    float* mbuf[2] = { MbufA, MbufB };
    for (int w = 1; w < n; ++w) {
        int CH = (w <= 2) ? 16 : 20;
        float* pout = pbuf[w & 1];
        float* pin  = pbuf[1 - (w & 1)];
        float* mout = mbuf[w & 1];
        float* min_ = mbuf[1 - (w & 1)];
        step_kernel<<<dim3(CH, B), 256, 0, stream>>>(
            unary, mrule, bmax, beta_n, E_TT, E_TN, E_NT, E_NN,
            pin, pout, min_, mout, w, n);
    }
    final_kernel<<<dim3(B), 32, 0, stream>>>(pbuf[(n - 1) & 1], mbuf[(n - 1) & 1],
                                             mrule, root, out, n);
}